// Round 14
// baseline (508.202 us; speedup 1.0000x reference)
//
#include <hip/hip_runtime.h>
#include <cstdint>

#define T_STEPS 200
#define B_TOTAL 8192
#define F_IN    40
#define H_DIM   128
#define C_OUT   5

#define CH      8                         // time steps per staged chunk
#define NCHUNK  (T_STEPS / CH)            // 25
#define CHB     (CH * F_IN * 4)           // 1280 bytes per chunk per b
#define WIN     2048                      // staged window bytes (2 x 1024)
#define ROWB    (T_STEPS * F_IN * 4)      // 32000 bytes per b

typedef float v2f __attribute__((ext_vector_type(2)));

// ds_read2_b32: dst = { LDS[addr + o0*4], LDS[addr + o1*4] }  (broadcast addr)
#define DSREAD2(dst, addr, o0, o1)                                             \
    asm volatile("ds_read2_b32 %0, %1 offset0:%c2 offset1:%c3"                 \
                 : "=v"(dst) : "v"(addr), "i"(o0), "i"(o1))

// v_pk_fma_f32 (VOP3P: all vector operands are VGPR pairs).
// acc = (acc_t, acc_t1); xp = (x_t[f], x_t1[f]); wpair = (w[2k], w[2k+1]).
// BW0 broadcasts word0 of wpair to both lanes (even f); BW1 word1 (odd f).
// Each 32-bit lane is an independent IEEE fp32 FMA — bit-identical to
// v_fma_f32 (op_sel broadcast mechanism validated bit-exact in r6/r7).
#define PKFMA_BW0(acc, xp, wpair)                                              \
    asm volatile("v_pk_fma_f32 %0, %1, %2, %0 op_sel:[0,0,0] op_sel_hi:[1,0,1]"\
                 : "+v"(acc) : "v"(xp), "v"(wpair))
#define PKFMA_BW1(acc, xp, wpair)                                              \
    asm volatile("v_pk_fma_f32 %0, %1, %2, %0 op_sel:[0,1,0] op_sel_hi:[1,1,1]"\
                 : "+v"(acc) : "v"(xp), "v"(wpair))

// async global->LDS, 16B per lane, dest = wave-uniform base + lane*16
__device__ __forceinline__ void gload_lds16(const void* g, void* l) {
    __builtin_amdgcn_global_load_lds(
        (const __attribute__((address_space(1))) void*)g,
        (__attribute__((address_space(3))) void*)l, 16, 0, 0);
}

__device__ __forceinline__ unsigned lds_addr(const void* p) {
    return (unsigned)(uintptr_t)(const __attribute__((address_space(3))) char*)p;
}

// ---------------------------------------------------------------------------
// Kernel A: layer-1 recurrence. Exact fp32 numerics (validated r2/r5-r9):
// per-step sequential-f FMA chain (f = 0..39), +b1, then ((0.9*m)+cur)-reset,
// each op individually rounded. Mapping: 2 waves per b; lane li owns ONE
// h = w*64+li -> 20 weight PAIRS = 40 VGPRs (vs r6-r9's 80 the allocator
// refused to keep). pk-FMA packs two consecutive TIME STEPS per instruction;
// ds_read2_b32 builds the (x_t[f], x_{t+1}[f]) pair in one LDS op.
// Per-wave-private staging windows, no barriers.
// ---------------------------------------------------------------------------
__global__ __launch_bounds__(256, 2)
void snn_l1(const float* __restrict__ x,
            const float* __restrict__ w1,
            const float* __restrict__ b1,
            unsigned long long* __restrict__ masks)
{
    __shared__ __align__(16) char xs[2][4][WIN];   // 16 KiB

    const int li = threadIdx.x & 63;
    const int wv = threadIdx.x >> 6;
    const int w  = wv & 1;                      // h-half: 0 -> h<64, 1 -> h>=64
    const int b  = blockIdx.x * 2 + (wv >> 1);  // grid 4096 -> b in [0,8192)
    const int h  = w * 64 + li;

    // one h row of w1 as 20 pairs: 40 VGPRs, register-resident
    v2f wp[F_IN / 2];
    {
        const v2f* wr = (const v2f*)(w1 + h * F_IN);
#pragma unroll
        for (int k = 0; k < F_IN / 2; ++k) wp[k] = wr[k];
    }
#pragma unroll
    for (int k = 0; k < F_IN / 2; ++k) asm volatile("" : "+v"(wp[k]));

    const float b1h = b1[h];
    float m = 0.0f, r = 0.0f;

    // per-lane global src: this b's row base + lane*16
    const char* xb = (const char*)x + (size_t)b * ROWB + (size_t)li * 16;

    auto winstart = [](int c) { return (c == NCHUNK - 1) ? (ROWB - WIN) : c * CHB; };

    // stage chunk 0 (each wave stages its own private copy)
    gload_lds16(xb + winstart(0),        &xs[0][wv][0]);
    gload_lds16(xb + winstart(0) + 1024, &xs[0][wv][1024]);
    asm volatile("s_waitcnt vmcnt(0)" ::: "memory");

    // mask element pointer: masks[(t*B_TOTAL + b)*2 + w], advance per t
    unsigned long long* mp = masks + ((size_t)b * 2 + w);

    for (int c = 0; c < NCHUNK; ++c) {
        if (c + 1 < NCHUNK) {
            const int ws = winstart(c + 1);
            gload_lds16(xb + ws,        &xs[(c + 1) & 1][wv][0]);
            gload_lds16(xb + ws + 1024, &xs[(c + 1) & 1][wv][1024]);
        }
        const int delta = c * CHB - winstart(c);       // 0, except last chunk
        const unsigned lbase = lds_addr(&xs[c & 1][wv][0]) + delta;

#pragma unroll
        for (int sp = 0; sp < CH / 2; ++sp) {          // two t-steps per iter
            const unsigned a = lbase + sp * 320;       // row t0; t0+1 at +160B
            v2f xp[8];
            v2f acc = {0.0f, 0.0f};
            // prime 8 pair-reads (f = 0..7)
#pragma unroll
            for (int j = 0; j < 8; ++j) DSREAD2(xp[j], a, j, j + F_IN);
            // 10 groups: wait(counted) -> 4 pk-FMA (f ascending) -> next reads
#pragma unroll
            for (int g = 0; g < 10; ++g) {
                if (g < 9) asm volatile("s_waitcnt lgkmcnt(4)" ::: "memory");
                else       asm volatile("s_waitcnt lgkmcnt(0)" ::: "memory");
                PKFMA_BW0(acc, xp[(4*g + 0) & 7], wp[2*g + 0]);   // f=4g
                PKFMA_BW1(acc, xp[(4*g + 1) & 7], wp[2*g + 0]);   // f=4g+1
                PKFMA_BW0(acc, xp[(4*g + 2) & 7], wp[2*g + 1]);   // f=4g+2
                PKFMA_BW1(acc, xp[(4*g + 3) & 7], wp[2*g + 1]);   // f=4g+3
                if (g < 8) {
#pragma unroll
                    for (int j = 0; j < 4; ++j) {
                        const int f2 = 4*g + 8 + j;
                        DSREAD2(xp[f2 & 7], a, f2, f2 + F_IN);
                    }
                }
            }
            // step t0 = c*8 + 2*sp (acc.x), then t0+1 (acc.y) — sequential
            m = __fsub_rn(__fadd_rn(__fmul_rn(0.9f, m), __fadd_rn(acc.x, b1h)), r);
            bool s0 = m > 1.0f;
            r = s0 ? 1.0f : 0.0f;
            unsigned long long bal = __ballot(s0);
            if (li == 0) *mp = bal;                    // 8B half of masks[t][b]
            mp += B_TOTAL * 2;

            m = __fsub_rn(__fadd_rn(__fmul_rn(0.9f, m), __fadd_rn(acc.y, b1h)), r);
            s0 = m > 1.0f;
            r = s0 ? 1.0f : 0.0f;
            bal = __ballot(s0);
            if (li == 0) *mp = bal;
            mp += B_TOTAL * 2;
        }
        asm volatile("s_waitcnt vmcnt(0)" ::: "memory");
    }
}

// ---------------------------------------------------------------------------
// Kernel B: cur2 sums, parallel over (t,b). Ascending-h individually-rounded
// adds of w2[c][h] over spiking h — identical numerics to the validated l2.
// ---------------------------------------------------------------------------
__global__ __launch_bounds__(256)
void snn_l2a(const ulonglong2* __restrict__ masks,
             const float* __restrict__ w2,
             float* __restrict__ cur2)
{
    __shared__ float w2s[H_DIM * C_OUT];   // [h][c] for bank spread
    const int tid = threadIdx.x;
    for (int i = tid; i < H_DIM * C_OUT; i += 256) {
        const int c = i / H_DIM, h = i % H_DIM;
        w2s[h * C_OUT + c] = w2[i];
    }
    __syncthreads();

    const size_t gid = (size_t)blockIdx.x * 256 + tid;   // == t*B_TOTAL + b
    const ulonglong2 mk = masks[gid];
    float s0 = 0.f, s1 = 0.f, s2 = 0.f, s3 = 0.f, s4 = 0.f;

    auto acc32 = [&](uint32_t w, int base) {
        while (w) {
            const int h = base + __builtin_ctz(w);
            w &= w - 1;
            const float* wp = &w2s[h * C_OUT];
            s0 = __fadd_rn(s0, wp[0]);
            s1 = __fadd_rn(s1, wp[1]);
            s2 = __fadd_rn(s2, wp[2]);
            s3 = __fadd_rn(s3, wp[3]);
            s4 = __fadd_rn(s4, wp[4]);
        }
    };
    acc32((uint32_t)(mk.x & 0xffffffffull), 0);
    acc32((uint32_t)(mk.x >> 32), 32);
    acc32((uint32_t)(mk.y & 0xffffffffull), 64);
    acc32((uint32_t)(mk.y >> 32), 96);

    float* o = cur2 + gid * C_OUT;
    o[0] = s0; o[1] = s1; o[2] = s2; o[3] = s3; o[4] = s4;
}

// ---------------------------------------------------------------------------
// Kernel C: layer-2 recurrence over t. Lane = (b,c), coalesced cur2/out,
// depth-4 static-unrolled prefetch. Ops identical to validated l2.
// ---------------------------------------------------------------------------
__global__ __launch_bounds__(256)
void snn_l2b(const float* __restrict__ cur2,
             const float* __restrict__ b2,
             float* __restrict__ out)
{
    const int gid = blockIdx.x * 256 + threadIdx.x;      // b*5 + c
    const float b2c = b2[gid % 5];
    const int STRIDE = B_TOTAL * C_OUT;                  // 40960
    float m2 = 0.0f, r2 = 0.0f;

    float f0 = cur2[0 * (size_t)STRIDE + gid];
    float f1 = cur2[1 * (size_t)STRIDE + gid];
    float f2 = cur2[2 * (size_t)STRIDE + gid];
    float f3 = cur2[3 * (size_t)STRIDE + gid];

#define L2B_STEP(F, TT)                                                        \
    {                                                                          \
        const float cur = __fadd_rn(F, b2c);                                   \
        m2 = __fsub_rn(__fadd_rn(__fmul_rn(0.9f, m2), cur), r2);               \
        const float s = (m2 > 1.0f) ? 1.0f : 0.0f;                             \
        r2 = s;                                                                \
        out[(size_t)(TT) * STRIDE + gid] = s;                                  \
        F = ((TT) + 4 < T_STEPS) ? cur2[(size_t)((TT) + 4) * STRIDE + gid]     \
                                 : 0.0f;                                       \
    }

    for (int t = 0; t < T_STEPS; t += 4) {
        L2B_STEP(f0, t + 0)
        L2B_STEP(f1, t + 1)
        L2B_STEP(f2, t + 2)
        L2B_STEP(f3, t + 3)
    }
#undef L2B_STEP
}

extern "C" void kernel_launch(void* const* d_in, const int* in_sizes, int n_in,
                              void* d_out, int out_size, void* d_ws, size_t ws_size,
                              hipStream_t stream) {
    const float* x  = (const float*)d_in[0];
    const float* w1 = (const float*)d_in[1];
    const float* b1 = (const float*)d_in[2];
    const float* w2 = (const float*)d_in[3];
    const float* b2 = (const float*)d_in[4];
    float* out = (float*)d_out;

    // ws layout: masks [t][b] 16B each = 26,214,400 B; cur2 [t][b][c] fp32 =
    // 32,768,000 B; total ~59 MB.
    unsigned long long* masks = (unsigned long long*)d_ws;
    float* cur2 = (float*)((char*)d_ws + (size_t)T_STEPS * B_TOTAL * 16);

    snn_l1 <<<dim3(B_TOTAL / 2),             dim3(256), 0, stream>>>(x, w1, b1, masks);
    snn_l2a<<<dim3(T_STEPS * B_TOTAL / 256), dim3(256), 0, stream>>>((const ulonglong2*)masks, w2, cur2);
    snn_l2b<<<dim3(B_TOTAL * C_OUT / 256),   dim3(256), 0, stream>>>(cur2, b2, out);
}

// Round 15
// 508.042 us; speedup vs baseline: 1.0003x; 1.0003x over previous
//
#include <hip/hip_runtime.h>
#include <cstdint>

#define T_STEPS 200
#define B_TOTAL 8192
#define F_IN    40
#define H_DIM   128
#define C_OUT   5

#define CH      8                         // time steps per staged chunk
#define NCHUNK  (T_STEPS / CH)            // 25
#define CHB     (CH * F_IN * 4)           // 1280 bytes per chunk per b
#define WIN     2048                      // staged window bytes (2 x 1024)
#define ROWB    (T_STEPS * F_IN * 4)      // 32000 bytes per b

typedef float v2f __attribute__((ext_vector_type(2)));

// ds_read2_b32: dst = { LDS[addr + o0*4], LDS[addr + o1*4] }  (broadcast addr)
#define DSREAD2(dst, addr, o0, o1)                                             \
    asm volatile("ds_read2_b32 %0, %1 offset0:%c2 offset1:%c3"                 \
                 : "=v"(dst) : "v"(addr), "i"(o0), "i"(o1))

// v_pk_fma_f32 (VOP3P; all vector operands are VGPR pairs).
// acc = (acc_t, acc_t1); xp = (x_t[f], x_t1[f]); wpair = (w[2k], w[2k+1]).
// BW0 broadcasts word0 of wpair to both words (even f); BW1 word1 (odd f).
// Each 32-bit word is an independent IEEE fp32 FMA — bit-identical to
// v_fma_f32 (mechanism validated bit-exact in r6/r7/r14 PASSes).
#define PKFMA_BW0(acc, xp, wpair)                                              \
    asm volatile("v_pk_fma_f32 %0, %1, %2, %0 op_sel:[0,0,0] op_sel_hi:[1,0,1]"\
                 : "+v"(acc) : "v"(xp), "v"(wpair))
#define PKFMA_BW1(acc, xp, wpair)                                              \
    asm volatile("v_pk_fma_f32 %0, %1, %2, %0 op_sel:[0,1,0] op_sel_hi:[1,1,1]"\
                 : "+v"(acc) : "v"(xp), "v"(wpair))

// async global->LDS, 16B per lane, dest = wave-uniform base + lane*16
__device__ __forceinline__ void gload_lds16(const void* g, void* l) {
    __builtin_amdgcn_global_load_lds(
        (const __attribute__((address_space(1))) void*)g,
        (__attribute__((address_space(3))) void*)l, 16, 0, 0);
}

__device__ __forceinline__ unsigned lds_addr(const void* p) {
    return (unsigned)(uintptr_t)(const __attribute__((address_space(3))) char*)p;
}

// ---------------------------------------------------------------------------
// Kernel A: layer-1 recurrence. Exact fp32 numerics (validated r2/r5-r9/r14):
// per-step sequential-f FMA chain (f = 0..39), +b1, then ((0.9*m)+cur)-reset,
// each op individually rounded. 2 waves per b; lane li owns ONE h = w*64+li.
// Register budget engineered to fit the allocator's 64-VGPR ceiling (r14
// post-mortem: volatile pins at ~70 pressure -> scratch spill, 520us):
//   40 weight VGPRs + 4-slot xp ring (8) + state/addr (~10) ~= 58.
// No pins (pressure < budget -> no remat incentive); wave-uniform offsets
// forced to SGPRs via readfirstlane. pk-FMA packs two TIME STEPS per
// instruction; ds_read2_b32 builds (x_t[f], x_{t+1}[f]) pairs. Per-wave-
// private staging windows, no barriers.
// ---------------------------------------------------------------------------
__global__ __launch_bounds__(256)
void snn_l1(const float* __restrict__ x,
            const float* __restrict__ w1,
            const float* __restrict__ b1,
            unsigned long long* __restrict__ masks)
{
    __shared__ __align__(16) char xs[2][4][WIN];   // 16 KiB

    const int li = threadIdx.x & 63;
    const int wv = threadIdx.x >> 6;
    const int w  = wv & 1;                      // h-half: 0 -> h<64, 1 -> h>=64
    const int b  = blockIdx.x * 2 + (wv >> 1);  // grid 4096 -> b in [0,8192)
    const int h  = w * 64 + li;

    // one h row of w1 as 20 pairs: 40 VGPRs
    v2f wp[F_IN / 2];
    {
        const v2f* wr = (const v2f*)(w1 + h * F_IN);
#pragma unroll
        for (int k = 0; k < F_IN / 2; ++k) wp[k] = wr[k];
    }

    const float b1h = b1[h];
    float m = 0.0f, r = 0.0f;

    // wave-uniform offsets -> SGPRs (saddr addressing; saves VGPR pairs)
    const int xo = __builtin_amdgcn_readfirstlane(b * ROWB);       // < 2^31
    const int mo = __builtin_amdgcn_readfirstlane(b * 2 + w);
    const char* xb = (const char*)x + xo + li * 16;                // per-lane src
    unsigned long long* mp = masks + mo;

    auto winstart = [](int c) { return (c == NCHUNK - 1) ? (ROWB - WIN) : c * CHB; };

    // stage chunk 0 (each wave stages its own private window)
    gload_lds16(xb + winstart(0),        &xs[0][wv][0]);
    gload_lds16(xb + winstart(0) + 1024, &xs[0][wv][1024]);
    asm volatile("s_waitcnt vmcnt(0)" ::: "memory");

    for (int c = 0; c < NCHUNK; ++c) {
        if (c + 1 < NCHUNK) {
            const int ws = winstart(c + 1);
            gload_lds16(xb + ws,        &xs[(c + 1) & 1][wv][0]);
            gload_lds16(xb + ws + 1024, &xs[(c + 1) & 1][wv][1024]);
        }
        const int delta = c * CHB - winstart(c);       // 0, except last chunk
        const unsigned lbase = lds_addr(&xs[c & 1][wv][0]) + delta;

#pragma unroll
        for (int sp = 0; sp < CH / 2; ++sp) {          // two t-steps per iter
            const unsigned a = lbase + sp * 320;       // row t0; t0+1 at +160B
            v2f xp[4];                                 // 4-slot ring (8 VGPRs)
            v2f acc = {0.0f, 0.0f};
            // prime 4 pair-reads (f = 0..3)
#pragma unroll
            for (int j = 0; j < 4; ++j) DSREAD2(xp[j], a, j, j + F_IN);
            // 20 groups: wait(counted) -> 2 pk-FMA (f = 2g, 2g+1) -> 2 reads
#pragma unroll
            for (int g = 0; g < 20; ++g) {
                if (g < 18) asm volatile("s_waitcnt lgkmcnt(2)" ::: "memory");
                else        asm volatile("s_waitcnt lgkmcnt(0)" ::: "memory");
                PKFMA_BW0(acc, xp[(2*g    ) & 3], wp[g]);   // f = 2g   (even)
                PKFMA_BW1(acc, xp[(2*g + 1) & 3], wp[g]);   // f = 2g+1 (odd)
                if (g < 18) {
                    const int f0 = 2*g + 4, f1 = 2*g + 5;
                    DSREAD2(xp[f0 & 3], a, f0, f0 + F_IN);
                    DSREAD2(xp[f1 & 3], a, f1, f1 + F_IN);
                }
            }
            // step t0 = c*8 + 2*sp (acc.x), then t0+1 (acc.y) — sequential
            m = __fsub_rn(__fadd_rn(__fmul_rn(0.9f, m), __fadd_rn(acc.x, b1h)), r);
            bool s0 = m > 1.0f;
            r = s0 ? 1.0f : 0.0f;
            unsigned long long bal = __ballot(s0);
            if (li == 0) *mp = bal;                    // 8B half of masks[t][b]
            mp += B_TOTAL * 2;

            m = __fsub_rn(__fadd_rn(__fmul_rn(0.9f, m), __fadd_rn(acc.y, b1h)), r);
            s0 = m > 1.0f;
            r = s0 ? 1.0f : 0.0f;
            bal = __ballot(s0);
            if (li == 0) *mp = bal;
            mp += B_TOTAL * 2;
        }
        asm volatile("s_waitcnt vmcnt(0)" ::: "memory");
    }
}

// ---------------------------------------------------------------------------
// Kernel B: cur2 sums, parallel over (t,b). Ascending-h individually-rounded
// adds of w2[c][h] over spiking h — identical numerics to the validated l2.
// ---------------------------------------------------------------------------
__global__ __launch_bounds__(256)
void snn_l2a(const ulonglong2* __restrict__ masks,
             const float* __restrict__ w2,
             float* __restrict__ cur2)
{
    __shared__ float w2s[H_DIM * C_OUT];   // [h][c] for bank spread
    const int tid = threadIdx.x;
    for (int i = tid; i < H_DIM * C_OUT; i += 256) {
        const int c = i / H_DIM, h = i % H_DIM;
        w2s[h * C_OUT + c] = w2[i];
    }
    __syncthreads();

    const size_t gid = (size_t)blockIdx.x * 256 + tid;   // == t*B_TOTAL + b
    const ulonglong2 mk = masks[gid];
    float s0 = 0.f, s1 = 0.f, s2 = 0.f, s3 = 0.f, s4 = 0.f;

    auto acc32 = [&](uint32_t w, int base) {
        while (w) {
            const int h = base + __builtin_ctz(w);
            w &= w - 1;
            const float* wp = &w2s[h * C_OUT];
            s0 = __fadd_rn(s0, wp[0]);
            s1 = __fadd_rn(s1, wp[1]);
            s2 = __fadd_rn(s2, wp[2]);
            s3 = __fadd_rn(s3, wp[3]);
            s4 = __fadd_rn(s4, wp[4]);
        }
    };
    acc32((uint32_t)(mk.x & 0xffffffffull), 0);
    acc32((uint32_t)(mk.x >> 32), 32);
    acc32((uint32_t)(mk.y & 0xffffffffull), 64);
    acc32((uint32_t)(mk.y >> 32), 96);

    float* o = cur2 + gid * C_OUT;
    o[0] = s0; o[1] = s1; o[2] = s2; o[3] = s3; o[4] = s4;
}

// ---------------------------------------------------------------------------
// Kernel C: layer-2 recurrence over t. Lane = (b,c), coalesced cur2/out,
// depth-4 static-unrolled prefetch. Ops identical to validated l2.
// ---------------------------------------------------------------------------
__global__ __launch_bounds__(256)
void snn_l2b(const float* __restrict__ cur2,
             const float* __restrict__ b2,
             float* __restrict__ out)
{
    const int gid = blockIdx.x * 256 + threadIdx.x;      // b*5 + c
    const float b2c = b2[gid % 5];
    const int STRIDE = B_TOTAL * C_OUT;                  // 40960
    float m2 = 0.0f, r2 = 0.0f;

    float f0 = cur2[0 * (size_t)STRIDE + gid];
    float f1 = cur2[1 * (size_t)STRIDE + gid];
    float f2 = cur2[2 * (size_t)STRIDE + gid];
    float f3 = cur2[3 * (size_t)STRIDE + gid];

#define L2B_STEP(F, TT)                                                        \
    {                                                                          \
        const float cur = __fadd_rn(F, b2c);                                   \
        m2 = __fsub_rn(__fadd_rn(__fmul_rn(0.9f, m2), cur), r2);               \
        const float s = (m2 > 1.0f) ? 1.0f : 0.0f;                             \
        r2 = s;                                                                \
        out[(size_t)(TT) * STRIDE + gid] = s;                                  \
        F = ((TT) + 4 < T_STEPS) ? cur2[(size_t)((TT) + 4) * STRIDE + gid]     \
                                 : 0.0f;                                       \
    }

    for (int t = 0; t < T_STEPS; t += 4) {
        L2B_STEP(f0, t + 0)
        L2B_STEP(f1, t + 1)
        L2B_STEP(f2, t + 2)
        L2B_STEP(f3, t + 3)
    }
#undef L2B_STEP
}

extern "C" void kernel_launch(void* const* d_in, const int* in_sizes, int n_in,
                              void* d_out, int out_size, void* d_ws, size_t ws_size,
                              hipStream_t stream) {
    const float* x  = (const float*)d_in[0];
    const float* w1 = (const float*)d_in[1];
    const float* b1 = (const float*)d_in[2];
    const float* w2 = (const float*)d_in[3];
    const float* b2 = (const float*)d_in[4];
    float* out = (float*)d_out;

    // ws layout: masks [t][b] 16B each = 26,214,400 B; cur2 [t][b][c] fp32 =
    // 32,768,000 B; total ~59 MB.
    unsigned long long* masks = (unsigned long long*)d_ws;
    float* cur2 = (float*)((char*)d_ws + (size_t)T_STEPS * B_TOTAL * 16);

    snn_l1 <<<dim3(B_TOTAL / 2),             dim3(256), 0, stream>>>(x, w1, b1, masks);
    snn_l2a<<<dim3(T_STEPS * B_TOTAL / 256), dim3(256), 0, stream>>>((const ulonglong2*)masks, w2, cur2);
    snn_l2b<<<dim3(B_TOTAL * C_OUT / 256),   dim3(256), 0, stream>>>(cur2, b2, out);
}